// Round 10
// baseline (626.497 us; speedup 1.0000x reference)
//
#include <hip/hip_runtime.h>
#include <hip/hip_bf16.h>
#include <math.h>

#define EPSV 1e-5f
#define IS3  0.57735026918962576f   // 1/sqrt(3)
#define PNRM 0.125f                 // 1/sqrt(2*32)

typedef __attribute__((ext_vector_type(8)))  short  short8;
typedef __attribute__((ext_vector_type(4)))  float  floatx4;
typedef __attribute__((ext_vector_type(16))) float  floatx16;

static __device__ inline unsigned short f2bf(float f) {
    unsigned int u = __float_as_uint(f);
    return (unsigned short)((u + 0x7fff + ((u >> 16) & 1)) >> 16);  // RNE
}
static __device__ inline unsigned int f2bf2(float lo, float hi) {   // packed cvt
    union { __hip_bfloat162 b; unsigned int u; } cv;
    cv.b = __float22bfloat162_rn(make_float2(lo, hi));
    return cv.u;
}
static __device__ inline float bflo(unsigned int u) { return __uint_as_float(u << 16); }
static __device__ inline float bfhi(unsigned int u) { return __uint_as_float(u & 0xffff0000u); }

// async global->LDS, 16B per lane; lds dest = uniform base + lane*16 (HW adds it)
#define GLD16(gp, lp) __builtin_amdgcn_global_load_lds( \
    (const __attribute__((address_space(1))) unsigned int*)(gp), \
    (__attribute__((address_space(3))) unsigned int*)(lp), 16, 0, 0)

// ---- K0: coalesced LDS-transpose f32 -> bf16 swizzled col-tiles, + zeroing.
// tile layout (shorts): tile*4096 + (k>>3)*256 + (c&31)*8 + (k&7)
__global__ __launch_bounds__(256) void k0_tile(const float* __restrict__ W2,
                                               const float* __restrict__ W1,
                                               unsigned short* __restrict__ W2T,
                                               unsigned short* __restrict__ W1T,
                                               int* __restrict__ zbase, int zn) {
    const int bx = blockIdx.x, tid = threadIdx.x;
    if (bx >= 132) {
        int i = (bx - 132) * 256 + tid;
        if (i < zn) zbase[i] = 0;
        return;
    }
    __shared__ float tile[128 * 33];
    const float* src;
    unsigned short* dst;
    int nc, tb;
    if (bx < 128) { src = W2; dst = W2T; nc = 4096; tb = bx; }
    else          { src = W1; dst = W1T; nc = 128;  tb = bx - 128; }
    const int c0 = tb * 32;
#pragma unroll
    for (int r = 0; r < 16; ++r) {
        int lin = r * 256 + tid;
        int k = lin >> 5, c = lin & 31;
        tile[k * 33 + c] = src[(size_t)k * nc + c0 + c];
    }
    __syncthreads();
#pragma unroll
    for (int r = 0; r < 2; ++r) {
        int g = r * 256 + tid;          // 0..511
        int kc = g >> 5, c = g & 31;
        union { unsigned int u[4]; short8 s; } v;
#pragma unroll
        for (int j = 0; j < 4; ++j)
            v.u[j] = f2bf2(tile[(kc * 8 + 2 * j) * 33 + c], tile[(kc * 8 + 2 * j + 1) * 33 + c]);
        *(short8*)(dst + (size_t)tb * 4096 + kc * 256 + c * 8) = v.s;
    }
}

// ---- K1: h = relu(ea @ W1 + b1) via MFMA 32x32x16.
// Writes h in the 16-edge A-fragment layout k2 reads directly:
// group g16 = e/16: short addr = g16*2048 + (kc*4+quad)*128 + (e&15)*8 + (k&7)
__global__ __launch_bounds__(256) void k1_fc(const float* __restrict__ ea,
                                             const unsigned short* __restrict__ W1T,
                                             const float* __restrict__ b1,
                                             const int* __restrict__ ei,
                                             unsigned short* __restrict__ hsw,
                                             int* __restrict__ deg, int E) {
    __shared__ __align__(16) unsigned short W1s[16384];        // 32 KB swizzled tiles
    __shared__ __align__(16) unsigned short bounce[4 * 1056];  // 8.4 KB
    const int tid = threadIdx.x, lane = tid & 63, wv = tid >> 6;
    const int half = lane >> 5, col = lane & 31;
    const int e0 = blockIdx.x * 128;

    if (tid < 128) { int e = e0 + tid; if (e < E) atomicAdd(&deg[ei[e]], 1); }

#pragma unroll
    for (int q = 0; q < 8; ++q) {
        int chunk = wv * 8 + q;
        GLD16((const char*)W1T + chunk * 1024 + lane * 16, (char*)W1s + chunk * 1024);
    }

    int e = e0 + wv * 32 + col; if (e >= E) e = E - 1;
    short8 afr[8];
#pragma unroll
    for (int c = 0; c < 8; ++c) {
        const float4* p = (const float4*)(ea + (size_t)e * 128 + c * 16 + half * 8);
        float4 f0 = p[0], f1 = p[1];
        union { unsigned int u[4]; short8 s; } v;
        v.u[0] = f2bf2(f0.x, f0.y); v.u[1] = f2bf2(f0.z, f0.w);
        v.u[2] = f2bf2(f1.x, f1.y); v.u[3] = f2bf2(f1.z, f1.w);
        afr[c] = v.s;
    }
    __syncthreads();

    unsigned short* myb = bounce + wv * 1056;   // 4 chunks x 264 shorts
    const int gbase = blockIdx.x * 8 + wv * 2;  // two 16-edge groups per wave
#pragma unroll
    for (int jt = 0; jt < 4; ++jt) {
        floatx16 d = {0,0,0,0,0,0,0,0,0,0,0,0,0,0,0,0};
#pragma unroll
        for (int c = 0; c < 8; ++c) {
            short8 bf = *(const short8*)((const char*)W1s + jt * 8192 + (2 * c + half) * 512 + col * 16);
            d = __builtin_amdgcn_mfma_f32_32x32x16_bf16(afr[c], bf, d, 0, 0, 0);
        }
        float b1v = b1[jt * 32 + col];
        // scatter MFMA regs into bounce: [chunk=col>>3][r][k7=col&7]
#pragma unroll
        for (int reg = 0; reg < 16; ++reg) {
            int r = (reg & 3) + 8 * (reg >> 2) + 4 * half;
            float v = d[reg] + b1v;
            v = v > 0.f ? v : 0.f;
            myb[(col >> 3) * 264 + r * 8 + (col & 7)] = f2bf(v);
        }
        // readback into 16-edge A-frag layout, coalesced 1KB stores
#pragma unroll
        for (int s = 0; s < 2; ++s) {
            int lin = s * 64 + lane;
            int g = lin >> 6, rem = lin & 63;
            int q = rem >> 4, el = rem & 15;
            short8 v = *(const short8*)&myb[q * 264 + (g * 16 + el) * 8];
            *(short8*)(hsw + (size_t)(gbase + g) * 2048 + (jt * 4 + q) * 128 + el * 8) = v;
        }
    }
}

// ---- K2: MFMA 16x16x32 GEMM (h @ W2) fused with TP contraction.
// 4 waves x 16 edges, NO u-split: all waves read identical B addresses ->
// within-block L1 dedup; alignment s_barrier every 8 tiles (no waitcnt).
// Single-accumulator out1 via phase-specific coef tables; no epilogue exchange.
__global__ __launch_bounds__(256, 3) void k2_mfma(const unsigned short* __restrict__ hsw,
                                                  const unsigned short* __restrict__ W2T,
                                                  const float* __restrict__ b2,
                                                  const float* __restrict__ na,
                                                  const int* __restrict__ ei,
                                                  const float* __restrict__ sh,
                                                  const int* __restrict__ rowptr,
                                                  int* __restrict__ cursor,
                                                  int* __restrict__ elist,
                                                  float* __restrict__ tp, int E) {
    __shared__ __align__(16) unsigned short Ctb[8 * 2048];  // 8 tables [32u][64el], 32 KB

    const int tid = threadIdx.x, lane = tid & 63, wv = tid >> 6;
    const int l15 = lane & 15, quad = lane >> 4;
    const int e0 = blockIdx.x * 64;

    // merged k_fill: bucket this block's edges into the CSR elist
    if (tid < 64) {
        int e = e0 + tid;
        if (e < E) {
            int s = ei[e];
            int pos = rowptr[s] + atomicAdd(&cursor[s], 1);
            elist[pos] = e;
        }
    }

    // coef tables (bf16), [u][el], fully pre-scaled:
    // T0 (b0): PNRM*x0*s0            T7 (b3): PNRM*IS3*(x1·sh1)
    // T1..3 (b1): PNRM*IS3*sh1_t*x0  T4..6 (b2): PNRM*IS3*s0*x1_t
    for (int idx = tid; idx < 2048; idx += 256) {
        int el = idx & 63, u = idx >> 6;
        int e = e0 + el; int ec = e < E ? e : E - 1;
        int dn = ei[E + ec];
        const float* nar = na + (size_t)dn * 128;
        float x0  = nar[u];
        float x10 = nar[32 + u * 3], x11 = nar[33 + u * 3], x12 = nar[34 + u * 3];
        const float* shr = sh + (size_t)ec * 4;
        float s0 = shr[0], s1 = shr[1], s2 = shr[2], s3 = shr[3];
        int o = u * 64 + el;
        Ctb[0 * 2048 + o] = f2bf(PNRM * x0 * s0);
        Ctb[1 * 2048 + o] = f2bf(PNRM * IS3 * s1 * x0);
        Ctb[2 * 2048 + o] = f2bf(PNRM * IS3 * s2 * x0);
        Ctb[3 * 2048 + o] = f2bf(PNRM * IS3 * s3 * x0);
        Ctb[4 * 2048 + o] = f2bf(PNRM * IS3 * s0 * x10);
        Ctb[5 * 2048 + o] = f2bf(PNRM * IS3 * s0 * x11);
        Ctb[6 * 2048 + o] = f2bf(PNRM * IS3 * s0 * x12);
        Ctb[7 * 2048 + o] = f2bf(PNRM * IS3 * (x10 * s1 + x11 * s2 + x12 * s3));
    }

    // A fragments: wave's 16 edges, K=128 (4 frags)
    const int g16 = blockIdx.x * 4 + wv;
    short8 afr[4];
#pragma unroll
    for (int kc = 0; kc < 4; ++kc)
        afr[kc] = *(const short8*)(hsw + (size_t)g16 * 2048 + (kc * 4 + quad) * 128 + l15 * 8);

    __syncthreads();

    float acc0[8] = {}, accT0[8] = {}, accT1[8] = {}, accT2[8] = {};
    const int elb = wv * 16 + quad * 4;
    const unsigned short* bbase = W2T + quad * 256 + l15 * 8;

#define LOADB(ct, bf, bv0, bv1) do {                                           \
        const unsigned short* _bp = bbase + (size_t)(ct) * 4096;               \
        _Pragma("unroll")                                                      \
        for (int _kc = 0; _kc < 4; ++_kc) {                                    \
            (bf)[_kc]     = *(const short8*)(_bp + _kc * 1024);                \
            (bf)[4 + _kc] = *(const short8*)(_bp + _kc * 1024 + 128);          \
        }                                                                      \
        (bv0) = b2[(ct) * 32 + l15];                                           \
        (bv1) = b2[(ct) * 32 + 16 + l15];                                      \
    } while (0)

#define COMPUTE(ct, bf, bv0, bv1) do {                                                        \
        const int _b = (ct) >> 5, _u = (ct) & 31;                                             \
        floatx4 d0 = {0,0,0,0}, d1 = {0,0,0,0};                                               \
        _Pragma("unroll")                                                                     \
        for (int _kc = 0; _kc < 4; ++_kc) {                                                   \
            d0 = __builtin_amdgcn_mfma_f32_16x16x32_bf16(afr[_kc], (bf)[_kc],     d0, 0,0,0); \
            d1 = __builtin_amdgcn_mfma_f32_16x16x32_bf16(afr[_kc], (bf)[4 + _kc], d1, 0,0,0); \
        }                                                                                     \
        const int _off = _u * 64 + elb;                                                       \
        if (_b == 0 || _b == 3) {                                                             \
            uint2 cv = *(const uint2*)&Ctb[(_b == 0 ? 0 : 7) * 2048 + _off];                  \
            float cf[4] = {bflo(cv.x), bfhi(cv.x), bflo(cv.y), bfhi(cv.y)};                   \
            _Pragma("unroll")                                                                 \
            for (int rr = 0; rr < 4; ++rr) {                                                  \
                acc0[rr]     += cf[rr] * (d0[rr] + (bv0));                                    \
                acc0[4 + rr] += cf[rr] * (d1[rr] + (bv1));                                    \
            }                                                                                 \
        } else {                                                                              \
            const int _tb = (_b == 1) ? 1 : 4;                                                \
            uint2 c0 = *(const uint2*)&Ctb[(_tb + 0) * 2048 + _off];                          \
            uint2 c1 = *(const uint2*)&Ctb[(_tb + 1) * 2048 + _off];                          \
            uint2 c2 = *(const uint2*)&Ctb[(_tb + 2) * 2048 + _off];                          \
            float f0[4] = {bflo(c0.x), bfhi(c0.x), bflo(c0.y), bfhi(c0.y)};                   \
            float f1[4] = {bflo(c1.x), bfhi(c1.x), bflo(c1.y), bfhi(c1.y)};                   \
            float f2[4] = {bflo(c2.x), bfhi(c2.x), bflo(c2.y), bfhi(c2.y)};                   \
            _Pragma("unroll")                                                                 \
            for (int rr = 0; rr < 4; ++rr) {                                                  \
                float v0 = d0[rr] + (bv0), v1 = d1[rr] + (bv1);                               \
                accT0[rr] += f0[rr] * v0; accT0[4 + rr] += f0[rr] * v1;                       \
                accT1[rr] += f1[rr] * v0; accT1[4 + rr] += f1[rr] * v1;                       \
                accT2[rr] += f2[rr] * v0; accT2[4 + rr] += f2[rr] * v1;                       \
            }                                                                                 \
        }                                                                                     \
    } while (0)

    short8 bA[8], bB[8];
    float a0, a1, c0v, c1v;
    LOADB(0, bA, a0, a1);
    LOADB(1, bB, c0v, c1v);
    for (int p = 0; p < 128; p += 2) {
        COMPUTE(p, bA, a0, a1);
        if (p + 2 < 128) LOADB(p + 2, bA, a0, a1);
        COMPUTE(p + 1, bB, c0v, c1v);
        if (p + 3 < 128) LOADB(p + 3, bB, c0v, c1v);
        if ((p & 7) == 6) __builtin_amdgcn_s_barrier();   // keep waves aligned for L1 reuse
    }
#undef LOADB
#undef COMPUTE

    // epilogue: direct stores (full u-sums per wave; no exchange)
#pragma unroll
    for (int wt = 0; wt < 2; ++wt) {
#pragma unroll
        for (int rr = 0; rr < 4; ++rr) {
            int e = e0 + elb + rr;
            if (e >= E) continue;
            int w = wt * 16 + l15;
            int reg = wt * 4 + rr;
            float* tpe = tp + (size_t)e * 128;
            tpe[w] = acc0[reg];
            tpe[32 + w * 3 + 0] = accT0[reg];
            tpe[32 + w * 3 + 1] = accT1[reg];
            tpe[32 + w * 3 + 2] = accT2[reg];
        }
    }
}

// ---- K_scan: exclusive prefix sum of deg -> rowptr (1 WG) ----
__global__ __launch_bounds__(1024) void k_scan(const int* __restrict__ deg,
                                               int* __restrict__ rowptr, int N) {
    __shared__ int part[1024];
    const int tid = threadIdx.x;
    const int chunk = (N + 1023) / 1024;
    const int base = tid * chunk;
    int s = 0;
    for (int i = 0; i < chunk; ++i) {
        int n = base + i;
        if (n < N) s += deg[n];
    }
    part[tid] = s;
    __syncthreads();
    for (int off = 1; off < 1024; off <<= 1) {
        int t = 0;
        if (tid >= off) t = part[tid - off];
        __syncthreads();
        if (tid >= off) part[tid] += t;
        __syncthreads();
    }
    int prefix = (tid == 0) ? 0 : part[tid - 1];
    for (int i = 0; i < chunk; ++i) {
        int n = base + i;
        if (n < N) { rowptr[n] = prefix; prefix += deg[n]; }
    }
    if (tid == 0) rowptr[N] = part[1023];
}

// ---- K4: per-node gather-mean + residual + BN stats ----
__global__ __launch_bounds__(256) void k4_gather(const float* __restrict__ tp,
                                                 const int* __restrict__ rowptr,
                                                 const int* __restrict__ elist,
                                                 const float* __restrict__ na,
                                                 float* __restrict__ pre,
                                                 float* __restrict__ stats, int N) {
    __shared__ float bns[96];
    const int tid = threadIdx.x;
    if (tid < 96) bns[tid] = 0.f;
    __syncthreads();
    const int o = tid & 127, hf = tid >> 7;
    for (int n = blockIdx.x * 2 + hf; n < N; n += gridDim.x * 2) {
        int r0 = rowptr[n], r1 = rowptr[n + 1];
        float s0 = 0.f, s1 = 0.f;
        int j = r0;
        for (; j + 1 < r1; j += 2) {
            s0 += tp[(size_t)elist[j] * 128 + o];
            s1 += tp[(size_t)elist[j + 1] * 128 + o];
        }
        if (j < r1) s0 += tp[(size_t)elist[j] * 128 + o];
        float s = s0 + s1;
        int dg = r1 - r0;
        float cf = (float)(dg > 0 ? dg : 1);
        float v = s / cf + na[(size_t)n * 128 + o];
        pre[(size_t)n * 128 + o] = v;
        if (o < 32) {
            atomicAdd(&bns[o], v);
            atomicAdd(&bns[32 + o], v * v);
        } else {
            atomicAdd(&bns[64 + (o - 32) / 3], v * v);
        }
    }
    __syncthreads();
    if (tid < 96) atomicAdd(&stats[tid], bns[tid]);
}

// ---- K5: apply batch norm ----
__global__ __launch_bounds__(256) void k5_bn(const float* __restrict__ pre,
                                             const float* __restrict__ stats,
                                             const float* __restrict__ bnw,
                                             const float* __restrict__ bnb,
                                             float* __restrict__ out, int N) {
    size_t idx = (size_t)blockIdx.x * 256 + threadIdx.x;
    if (idx >= (size_t)N * 128) return;
    int o = (int)(idx & 127);
    float v = pre[idx];
    float invN = 1.f / (float)N;
    if (o < 32) {
        float m   = stats[o] * invN;
        float var = stats[32 + o] * invN - m * m;
        out[idx] = (v - m) * rsqrtf(var + EPSV) * bnw[o] + bnb[o];
    } else {
        int j = (o - 32) / 3;
        float vn = rsqrtf(stats[64 + j] * invN * (1.f / 3.f) + EPSV);
        out[idx] = v * vn * bnw[32 + j];
    }
}

extern "C" void kernel_launch(void* const* d_in, const int* in_sizes, int n_in,
                              void* d_out, int out_size, void* d_ws, size_t ws_size,
                              hipStream_t stream) {
    const float* node_attr  = (const float*)d_in[0];
    const int*   edge_index = (const int*)d_in[1];
    const float* edge_attr  = (const float*)d_in[2];
    const float* edge_sh    = (const float*)d_in[3];
    const float* W1  = (const float*)d_in[4];
    const float* b1  = (const float*)d_in[5];
    const float* W2  = (const float*)d_in[6];
    const float* b2  = (const float*)d_in[7];
    const float* bnw = (const float*)d_in[8];
    const float* bnb = (const float*)d_in[9];

    const int N = in_sizes[0] / 128;
    const int E = in_sizes[1] / 2;
    const int ngroups = ((E + 127) / 128) * 8;    // 16-edge groups

    float* tp     = (float*)d_ws;                 // E*128
    float* pre    = tp + (size_t)E * 128;         // N*128
    float* stats  = pre + (size_t)N * 128;        // 96
    int*   deg    = (int*)(stats + 96);           // N
    int*   cursor = deg + N;                      // N
    int*   rowptr = cursor + N;                   // N+1
    int*   elist  = rowptr + N + 1;               // E
    char* pbase = (char*)(elist + E);
    pbase += (16 - ((size_t)pbase & 15)) & 15;    // align 16
    unsigned short* hsw = (unsigned short*)pbase;          // ngroups*2048 bf16
    unsigned short* W2T = hsw + (size_t)ngroups * 2048;    // 524288
    unsigned short* W1T = W2T + (size_t)524288;            // 16384

    const int zn = 96 + 2 * N;                    // stats+deg+cursor (contiguous)
    const int zblocks = (zn + 255) / 256;

    k0_tile<<<132 + zblocks, 256, 0, stream>>>(W2, W1, W2T, W1T, (int*)stats, zn);
    k1_fc<<<(E + 127) / 128, 256, 0, stream>>>(edge_attr, W1T, b1, edge_index, hsw, deg, E);
    k_scan<<<1, 1024, 0, stream>>>(deg, rowptr, N);
    k2_mfma<<<(E + 63) / 64, 256, 0, stream>>>(hsw, W2T, b2, node_attr, edge_index,
                                               edge_sh, rowptr, cursor, elist, tp, E);
    k4_gather<<<1024, 256, 0, stream>>>(tp, rowptr, elist, node_attr, pre, stats, N);
    size_t ntot = (size_t)N * 128;
    k5_bn<<<(int)((ntot + 255) / 256), 256, 0, stream>>>(pre, stats, bnw, bnb,
                                                         (float*)d_out, N);
}